// Round 6
// baseline (234.631 us; speedup 1.0000x reference)
//
#include <hip/hip_runtime.h>

#define SEQ   4096
#define EMB   1280
#define NH    16
#define HD    80
#define HDP   96
#define O3    3840
#define SEGLEN 1024
#define NSEG  4
// sqrt(80) * log2(e): scores computed in log2 domain -> softmax uses native v_exp_f32 (exp2)
#define QSCALE (8.94427190999915878564f * 1.44269504088896340736f)

typedef unsigned short u16;
typedef __attribute__((ext_vector_type(8))) _Float16 f16x8;
typedef __attribute__((ext_vector_type(4))) _Float16 f16x4;
typedef __attribute__((ext_vector_type(2))) __fp16   h16x2;
typedef __attribute__((ext_vector_type(4))) float    f32x4;

__device__ __forceinline__ float ex2(float x) { return __builtin_amdgcn_exp2f(x); }

__device__ __forceinline__ u16 f2h(float f) {
  union { _Float16 h; u16 u; } v; v.h = (_Float16)f; return v.u;
}
__device__ __forceinline__ float h2f(u16 b) {
  union { u16 u; _Float16 h; } v; v.u = b; return (float)v.h;
}
__device__ __forceinline__ f32x4 exp2_4(f32x4 x) {
  f32x4 r; r.x = ex2(x.x); r.y = ex2(x.y); r.z = ex2(x.z); r.w = ex2(x.w); return r;
}
__device__ __forceinline__ f16x4 pk4(f32x4 s) {
  union { h16x2 h[2]; f16x4 f; } u;
  u.h[0] = __builtin_amdgcn_cvt_pkrtz(s.x, s.y);
  u.h[1] = __builtin_amdgcn_cvt_pkrtz(s.z, s.w);
  return u.f;
}
// async global->LDS, 16B per lane. LDS dest must be wave-uniform base + lane*16.
__device__ __forceinline__ void gl2lds16(const u16* g, u16* l) {
  __builtin_amdgcn_global_load_lds(
      (const __attribute__((address_space(1))) unsigned int*)g,
      (__attribute__((address_space(3))) unsigned int*)l, 16, 0, 0);
}

// ---------------- fused fp32 -> fp16 convert for hs, w_qkv, w_proj ----------------
#define CVT_N1 (SEQ * EMB / 4)
#define CVT_N2 (O3 * EMB / 4)
#define CVT_N3 (EMB * EMB / 4)
__global__ void cvt_all_kernel(const float* __restrict__ a, const float* __restrict__ b,
                               const float* __restrict__ c, u16* __restrict__ oa,
                               u16* __restrict__ ob, u16* __restrict__ oc) {
  int i = blockIdx.x * blockDim.x + threadIdx.x;
  const float* src; u16* dst; int j = i;
  if (j < CVT_N1)                { src = a; dst = oa; }
  else if (j < CVT_N1 + CVT_N2)  { src = b; dst = ob; j -= CVT_N1; }
  else                           { src = c; dst = oc; j -= CVT_N1 + CVT_N2; }
  float4 f = ((const float4*)src)[j];
  union { u16 h[4]; uint2 v; } o;
  o.h[0] = f2h(f.x); o.h[1] = f2h(f.y); o.h[2] = f2h(f.z); o.h[3] = f2h(f.w);
  ((uint2*)dst)[j] = o.v;
}

// ---------------- fp16 MFMA GEMM (128x128 tile, 2-barrier) -- kept for proj ----------------
// XCD-chunked swizzle: grid must be divisible by 8 (proj: 10x32=320 -> 40 blocks/XCD,
// bm in [4x,4x+4) per XCD -> A-panel L2 locality).
template<int OUTF>
__global__ __launch_bounds__(256)
void gemm_bias_kernel(const u16* __restrict__ A, const u16* __restrict__ W,
                      const float* __restrict__ bias, void* __restrict__ Cout,
                      int N, int K) {
  __shared__ u16 As[128][64];
  __shared__ u16 Bs[128][64];
  const int tid  = threadIdx.x;
  const int flat = blockIdx.x + gridDim.x * blockIdx.y;
  const int cpx  = (gridDim.x * gridDim.y) >> 3;
  const int nid  = (flat & 7) * cpx + (flat >> 3);
  const int bm   = nid / gridDim.x, bn = nid % gridDim.x;
  const int lane = tid & 63;
  const int wid  = tid >> 6;
  const int wm   = (wid >> 1) * 64, wn = (wid & 1) * 64;
  const int lr   = lane & 15, quad = lane >> 4;

  f32x4 acc[4][4];
  const f32x4 z4 = {0.f, 0.f, 0.f, 0.f};
  #pragma unroll
  for (int i = 0; i < 4; ++i)
    #pragma unroll
    for (int j = 0; j < 4; ++j) acc[i][j] = z4;

  const int arow = tid >> 3;                       // 0..31
  const int acol = (((tid & 7) ^ (arow & 7)) * 8); // swizzled GLOBAL col chunk
  const u16* Ab = A + (size_t)(bm * 128) * K;
  const u16* Wb = W + (size_t)(bn * 128) * K;
  u16* AsL = &As[0][0] + tid * 8;
  u16* BsL = &Bs[0][0] + tid * 8;

  for (int kt = 0; kt < K; kt += 64) {
    #pragma unroll
    for (int r = 0; r < 4; ++r) {
      gl2lds16(&Ab[(size_t)(arow + r * 32) * K + kt + acol], AsL + r * 2048);
      gl2lds16(&Wb[(size_t)(arow + r * 32) * K + kt + acol], BsL + r * 2048);
    }
    __syncthreads();
    #pragma unroll
    for (int k32 = 0; k32 < 2; ++k32) {
      const int c = (((k32 * 4 + quad) ^ (lr & 7)) * 8);
      f16x8 aF[4], bF[4];
      #pragma unroll
      for (int i = 0; i < 4; ++i) {
        aF[i] = *(const f16x8*)&As[wm + i * 16 + lr][c];
        bF[i] = *(const f16x8*)&Bs[wn + i * 16 + lr][c];
      }
      #pragma unroll
      for (int i = 0; i < 4; ++i)
        #pragma unroll
        for (int j = 0; j < 4; ++j)
          acc[i][j] = __builtin_amdgcn_mfma_f32_16x16x32_f16(aF[i], bF[j], acc[i][j], 0, 0, 0);
    }
    __syncthreads();
  }

  #pragma unroll
  for (int i = 0; i < 4; ++i) {
    int rowb = bm * 128 + wm + i * 16 + quad * 4;
    #pragma unroll
    for (int j = 0; j < 4; ++j) {
      int col = bn * 128 + wn + j * 16 + lr;
      float bv = bias[col];
      #pragma unroll
      for (int r = 0; r < 4; ++r) {
        float v = acc[i][j][r] + bv;
        if (OUTF) ((float*)Cout)[(size_t)(rowb + r) * N + col] = v;
        else      ((u16*)Cout)[(size_t)(rowb + r) * N + col] = f2h(v);
      }
    }
  }
}

// ---------------- fp16 MFMA GEMM 256x256, BK=64, 8 waves, single-region K-tiles ----------
// XCD-chunked swizzle: 240 blocks = 8 x 30 -> XCD x gets bm in {2x,2x+1}.
// Per K-tile t (buf=t&1, nb=buf^1): ONE barrier region:
//   issue 8 gl2lds staging tile t+1 -> nb        (pinned first by sched_barrier)
//   64 MFMA + 32 ds_read_b128, compiler-interleaved (fine-grained lgkmcnt; LDS unit
//   overlaps the MFMA pipe instead of lockstep phases -- the R5 stall was this serialization)
//   s_waitcnt vmcnt(0)  (t+1's loads had the whole tile's compute to land -> cheap)
//   s_barrier
// Barriers: 1/tile (was 8); full lgkm drains: 0 (was 4).
__global__ __launch_bounds__(512, 2)
void gemm256_kernel(const u16* __restrict__ A, const u16* __restrict__ W,
                    const float* __restrict__ bias, u16* __restrict__ Cout,
                    int N, int K) {
  __shared__ u16 As[2][256][64];   // 64 KiB
  __shared__ u16 Bs[2][256][64];   // 64 KiB
  const int tid  = threadIdx.x;
  const int flat = blockIdx.x + gridDim.x * blockIdx.y;   // bn-fastest dispatch order
  const int cpx  = (gridDim.x * gridDim.y) >> 3;          // blocks per XCD (30)
  const int nid  = (flat & 7) * cpx + (flat >> 3);
  const int bm   = nid / gridDim.x, bn = nid % gridDim.x;
  const int lane = tid & 63;
  const int wid  = tid >> 6;       // 0..7
  const int wm   = wid >> 2;       // 0..1 (M half within wave grid)
  const int wn   = wid & 3;        // 0..3
  const int lr   = lane & 15, quad = lane >> 4;
  const int NT   = K >> 6;         // K-tiles of 64

  const u16* Ab = A + (size_t)(bm * 256) * K;
  const u16* Wb = W + (size_t)(bn * 256) * K;

  // staging lane geometry: one gl2lds round = 64 rows x 64 cols (512 lanes x 16B)
  const int srr  = tid >> 3;                        // 0..63
  const int scol = ((tid & 7) ^ (srr & 7)) << 3;    // pre-swizzled global col chunk
  const u16* ApL = Ab + (size_t)srr * K + scol;
  const u16* WpL = Wb + (size_t)srr * K + scol;

  // stage a full K-tile t into buffer b: 8 gl2lds/thread (A 4 + B 4)
  auto stage = [&](int b, int t) {
    #pragma unroll
    for (int r = 0; r < 4; ++r)
      gl2lds16(ApL + (size_t)(r * 64) * K + t * 64, &As[b][r * 64][0] + tid * 8);
    #pragma unroll
    for (int r = 0; r < 4; ++r)
      gl2lds16(WpL + (size_t)(r * 64) * K + t * 64, &Bs[b][r * 64][0] + tid * 8);
  };

  f32x4 acc[8][4];
  const f32x4 z4 = {0.f, 0.f, 0.f, 0.f};
  #pragma unroll
  for (int i = 0; i < 8; ++i)
    #pragma unroll
    for (int j = 0; j < 4; ++j) acc[i][j] = z4;

  // prologue: stage tile 0, drain, barrier
  stage(0, 0);
  asm volatile("s_waitcnt vmcnt(0)" ::: "memory");
  __builtin_amdgcn_s_barrier();
  __builtin_amdgcn_sched_barrier(0);

  for (int t = 0; t < NT; ++t) {
    const int buf = t & 1, nb = buf ^ 1;
    // issue next tile's staging loads first (they complete under this tile's compute)
    if (t + 1 < NT) stage(nb, t + 1);
    __builtin_amdgcn_sched_barrier(0);

    __builtin_amdgcn_s_setprio(1);
    #pragma unroll
    for (int mq = 0; mq < 2; ++mq) {
      #pragma unroll
      for (int k32 = 0; k32 < 2; ++k32) {
        const int c = (((k32 * 4 + quad) ^ (lr & 7)) << 3);
        f16x8 aF[4], bF[4];
        #pragma unroll
        for (int i = 0; i < 4; ++i)
          aF[i] = *(const f16x8*)&As[buf][mq * 128 + wm * 64 + i * 16 + lr][c];
        #pragma unroll
        for (int j = 0; j < 4; ++j)
          bF[j] = *(const f16x8*)&Bs[buf][wn * 64 + j * 16 + lr][c];
        #pragma unroll
        for (int i = 0; i < 4; ++i)
          #pragma unroll
          for (int j = 0; j < 4; ++j)
            acc[mq * 4 + i][j] =
                __builtin_amdgcn_mfma_f32_16x16x32_f16(aF[i], bF[j], acc[mq * 4 + i][j], 0, 0, 0);
      }
    }
    __builtin_amdgcn_s_setprio(0);

    // next tile fully staged (issued one full compute phase ago)
    asm volatile("s_waitcnt vmcnt(0)" ::: "memory");
    __builtin_amdgcn_s_barrier();
    __builtin_amdgcn_sched_barrier(0);
  }

  // epilogue: bias add, fp16 store
  #pragma unroll
  for (int mq = 0; mq < 2; ++mq) {
    #pragma unroll
    for (int i = 0; i < 4; ++i) {
      const int rowb = bm * 256 + mq * 128 + wm * 64 + i * 16 + quad * 4;
      #pragma unroll
      for (int j = 0; j < 4; ++j) {
        const int col = bn * 256 + wn * 64 + j * 16 + lr;
        const float bv = bias[col];
        #pragma unroll
        for (int r = 0; r < 4; ++r)
          Cout[(size_t)(rowb + r) * N + col] = f2h(acc[mq * 4 + i][j][r] + bv);
      }
    }
  }
}

// ---------------- RoPE + layout reorg (fully vectorized IO via LDS) ----------------
// block = (64 s-rows, 1 head). qkv[s][3840] -> Qp[h][s][96] (*QSCALE), Kp[h][s][96], Vt[h][d][s]
__global__ __launch_bounds__(256)
void rope_reorg_kernel(const u16* __restrict__ qkv, const float* __restrict__ cosp,
                       const float* __restrict__ sinp, u16* __restrict__ Qp,
                       u16* __restrict__ Kp, u16* __restrict__ Vt) {
  __shared__ u16 Qs[64][80];
  __shared__ u16 Ks[64][80];
  __shared__ u16 Vs[64][88];   // stride 88: rows 16B aligned; col reads conflict-light
  const int tid = threadIdx.x;
  const int s0 = blockIdx.x * 64;
  const int h  = blockIdx.y;

  // load: 64 rows x 80 u16 x 3 arrays, uint4 vectorized
  for (int t = tid; t < 640; t += 256) {
    int r = t / 10, c = (t % 10) * 8;
    size_t g = (size_t)(s0 + r) * O3 + h * HD + c;
    *(uint4*)&Qs[r][c] = *(const uint4*)&qkv[g];
    *(uint4*)&Ks[r][c] = *(const uint4*)&qkv[g + EMB];
    *(uint4*)&Vs[r][c] = *(const uint4*)&qkv[g + 2 * EMB];
  }
  __syncthreads();

  // phase A: rope, 4 outputs per slot, uint2 writes
  for (int t = tid; t < 64 * 24; t += 256) {
    int r = t / 24, d4 = (t % 24) * 4;
    int s = s0 + r;
    size_t po = ((size_t)h * SEQ + s) * HDP + d4;
    if (d4 >= HD) {
      uint2 z = make_uint2(0, 0);
      *(uint2*)&Qp[po] = z; *(uint2*)&Kp[po] = z;
      continue;
    }
    float4 cv = *(const float4*)&cosp[(size_t)s * HD + d4];
    float4 sv = *(const float4*)&sinp[(size_t)s * HD + d4];
    int dp4 = (d4 < 40) ? d4 + 40 : d4 - 40;
    float sgn = (d4 < 40) ? -1.f : 1.f;
    union { u16 h[4]; uint2 v; } oq, ok;
    const float* cp = (const float*)&cv;
    const float* sp = (const float*)&sv;
    #pragma unroll
    for (int j = 0; j < 4; ++j) {
      float q  = h2f(Qs[r][d4 + j]),  k  = h2f(Ks[r][d4 + j]);
      float qp = h2f(Qs[r][dp4 + j]), kp = h2f(Ks[r][dp4 + j]);
      oq.h[j] = f2h((q * cp[j] + sgn * qp * sp[j]) * QSCALE);
      ok.h[j] = f2h(k * cp[j] + sgn * kp * sp[j]);
    }
    *(uint2*)&Qp[po] = oq.v;
    *(uint2*)&Kp[po] = ok.v;
  }

  // phase B: V transpose, uint4 writes along s
  for (int t = tid; t < HD * 8; t += 256) {
    int d = t / 8, sc = (t % 8) * 8;
    union { u16 h[8]; uint4 v; } o;
    #pragma unroll
    for (int j = 0; j < 8; ++j) o.h[j] = Vs[sc + j][d];
    *(uint4*)&Vt[((size_t)(h * HD + d)) * SEQ + s0 + sc] = o.v;
  }
}

// ---------------- flash attention: 128q blocks, triple-buffered counted-vmcnt pipeline ----
// block = 128 q x (head, seg), 8 waves x 16 q, 512 threads. S^T = K Q^T; P direct-to-MFMA.
// XCD-chunked swizzle: 512 blocks = 8 x 64 -> each XCD owns 8 complete (h,seg) groups;
// per-XCD K/V working set = 8 x 356KB = 2.9MB < 4MB L2 (was: all groups on all XCDs).
// K_l [3][64][96] per-row chunk swizzle (bank-spread). V_l [3][96][64] 16B-chunk XOR
// swizzle; rows 80..95 ones/zero so row-sum l is a 6th PV acc.
// Pipeline: stage tile t+2 at iter t into buf[(t+2)%3]; end-of-iter s_waitcnt vmcnt(3).
__global__ __launch_bounds__(512)
void attn_kernel(const u16* __restrict__ Qp, const u16* __restrict__ Kp,
                 const u16* __restrict__ Vt, u16* __restrict__ attnO) {
  __shared__ u16 K_l[3][64][96];   // 3 x 12 KiB
  __shared__ u16 V_l[3][96][64];   // 3 x 12 KiB
  const int BUFSZ = 6144;          // u16 per buffer (same for K and V)

  const int tid = threadIdx.x;     // 0..511
  const int lane = tid & 63, w = tid >> 6;   // w 0..7
  const int lr = lane & 15, quad = lane >> 4;
  // XCD-chunked remap: flat = bx + 8*by + 128*bz (dispatch order); nid groups 8 blocks
  // of one (h,seg) pair onto one XCD.
  const int flat = blockIdx.x + 8 * blockIdx.y + 128 * blockIdx.z;
  const int nid  = (flat & 7) * 64 + (flat >> 3);
  const int qb   = nid & 7;
  const int h    = (nid >> 3) & 15;
  const int sg   = nid >> 7;
  const int seg0 = sg * SEGLEN;
  const int q0b = seg0 + qb * 128;

  // Q B-fragments (q already scaled by sqrt(80)*log2e at rope time)
  f16x8 qF[3];
  {
    int qrow = q0b + w * 16 + lr;
    #pragma unroll
    for (int kc = 0; kc < 3; ++kc)
      qF[kc] = *(const f16x8*)&Qp[((size_t)h * SEQ + qrow) * HDP + kc * 32 + quad * 8];
  }
  // force-retire qF loads NOW so the compiler's waitcnt insertion marks them complete
  // before the pipelined loop (else it may inject vmcnt(0) at first use inside the loop)
  asm volatile("" :: "v"(qF[0]), "v"(qF[1]), "v"(qF[2]));
  asm volatile("s_waitcnt vmcnt(0)" ::: "memory");

  // ones/zero pad rows 80..95 of each V buffer (row 80 = 1.0h). 2 u16/thread/buffer.
  {
    u16 val = (tid < 32) ? (u16)0x3C00 : (u16)0;
    #pragma unroll
    for (int b = 0; b < 3; ++b) {
      u16* q = &V_l[0][0][0] + b * BUFSZ + 80 * 64 + tid * 2;
      q[0] = val; q[1] = val;
    }
  }

  // staging slot map: 3 rounds x 512 threads = 1536 slots/tile.
  //   s <  768 : K slot s   (r=s/12, c=s%12, chunk-swizzled source)
  //   s < 1408 : V slot s-768 (rv=sv/8, cv=sv%8, XOR-swizzled source)
  //   s >=1408 : duplicate of V slot s-1408 (uniform count filler; same data, same dest)
  const u16* Kbase = Kp + ((size_t)h * SEQ + seg0) * HDP;
  const u16* Vbase = Vt + (size_t)h * HD * SEQ + seg0;
  const u16* pG[3]; u16* dB[3]; int gAdv[3];
  #pragma unroll
  for (int t = 0; t < 3; ++t) {
    int s = t * 512 + tid;
    if (s < 768) {
      int r = s / 12, c = s % 12;
      int ck = (c & ~3) | ((c & 3) ^ ((r >> 1) & 3));  // K chunk swizzle (bank-spread)
      pG[t] = Kbase + (size_t)r * HDP + ck * 8;
      dB[t] = &K_l[0][0][0] + s * 8;
      gAdv[t] = 64 * HDP;
    } else {
      int sv = (s < 1408) ? s - 768 : s - 1408;
      int rv = sv / 8, cv = sv % 8;
      int cg = cv ^ (rv & 7);                          // V XOR chunk swizzle
      pG[t] = Vbase + (size_t)rv * SEQ + cg * 8;
      dB[t] = &V_l[0][0][0] + sv * 8;
      gAdv[t] = 64;
    }
  }

  // stage one K/V tile into buffer b (3 gl2lds/thread), advance global ptrs by 64 keys
  auto stage_adv = [&](int b) {
    #pragma unroll
    for (int t = 0; t < 3; ++t) {
      gl2lds16(pG[t], dB[t] + b * BUFSZ);
      pG[t] += gAdv[t];
    }
  };

  const f32x4 z4 = {0.f, 0.f, 0.f, 0.f};
  float m_r = -3.0e38f;
  f32x4 Oacc[6];   // [0..4] = output cols, [5] = MFMA row-sum (ones column of V)
  #pragma unroll
  for (int n = 0; n < 6; ++n) Oacc[n] = z4;

  const int kswz = (lr >> 1) & 3;  // == ((ct*16+lr)>>1)&3 for all ct

  // prologue: stage tiles 0,1; wait tile0 (3 newest = tile1 may fly); drain ds_writes
  stage_adv(0);
  stage_adv(1);
  asm volatile("s_waitcnt vmcnt(3) lgkmcnt(0)" ::: "memory");
  __builtin_amdgcn_s_barrier();
  __builtin_amdgcn_sched_barrier(0);

  int buf = 0, sb = 2;
  for (int kt = 0; kt < SEGLEN; kt += 64) {
    // issue stage of tile t+2 into buf[(t+2)%3]; its dest buffer's readers finished
    // at iter t-1 (barrier-separated). Completes by end of iter t+1 (vmcnt(3) chain).
    if (kt + 128 < SEGLEN) stage_adv(sb);

    const u16* kb = &K_l[0][0][0] + buf * BUFSZ;
    const u16* vb = &V_l[0][0][0] + buf * BUFSZ;

    // S^T = K Q^T: lane holds scores for q=lr at c = ct*16 + quad*4 + r (log2 domain)
    f32x4 S[4];
    __builtin_amdgcn_s_setprio(1);
    #pragma unroll
    for (int ct = 0; ct < 4; ++ct) {
      S[ct] = z4;
      #pragma unroll
      for (int kc = 0; kc < 3; ++kc) {
        f16x8 kF = *(const f16x8*)&kb[(ct * 16 + lr) * 96 + kc * 32 + ((quad ^ kswz) << 3)];
        S[ct] = __builtin_amdgcn_mfma_f32_16x16x32_f16(kF, qF[kc], S[ct], 0, 0, 0);
      }
    }
    __builtin_amdgcn_s_setprio(0);

    // online softmax (exp2 domain): max tree + 2 shuffles; row-sum comes from PV MFMA
    float mx = fmaxf(fmaxf(S[0].x, S[0].y), fmaxf(S[0].z, S[0].w));
    #pragma unroll
    for (int ct = 1; ct < 4; ++ct)
      mx = fmaxf(mx, fmaxf(fmaxf(S[ct].x, S[ct].y), fmaxf(S[ct].z, S[ct].w)));
    mx = fmaxf(mx, __shfl_xor(mx, 16, 64));
    mx = fmaxf(mx, __shfl_xor(mx, 32, 64));
    float mnew = fmaxf(m_r, mx);
    float alpha = ex2(m_r - mnew);
    m_r = mnew;

    f32x4 mv = {mnew, mnew, mnew, mnew};
    #pragma unroll
    for (int ct = 0; ct < 4; ++ct) S[ct] = exp2_4(S[ct] - mv);

    // rescale history only when some lane's max moved (wave-uniform skip)
    if (__ballot(alpha != 1.0f)) {
      f32x4 al;
      al.x = __shfl(alpha, quad * 4 + 0, 64);
      al.y = __shfl(alpha, quad * 4 + 1, 64);
      al.z = __shfl(alpha, quad * 4 + 2, 64);
      al.w = __shfl(alpha, quad * 4 + 3, 64);
      #pragma unroll
      for (int n = 0; n < 6; ++n) Oacc[n] *= al;
    }

    // P fragments via packed cvt, direct A-operand of 16x16x16 (k=quad*4+j == c=quad*4+r)
    f16x4 pF[4];
    #pragma unroll
    for (int ct = 0; ct < 4; ++ct) pF[ct] = pk4(S[ct]);

    // PV: vF from swizzled V_l; n=5 hits the ones/zero rows -> row-sum accumulator
    __builtin_amdgcn_s_setprio(1);
    #pragma unroll
    for (int ct = 0; ct < 4; ++ct) {
      const int cchunk = 2 * ct + (quad >> 1);
      #pragma unroll
      for (int n = 0; n < 6; ++n) {
        int vrow = n * 16 + lr;
        const u16* vp = vb + vrow * 64 + ((cchunk ^ (vrow & 7)) << 3) + ((quad & 1) << 2);
        f16x4 vF = *(const f16x4*)vp;
        Oacc[n] = __builtin_amdgcn_mfma_f32_16x16x16f16(pF[ct], vF, Oacc[n], 0, 0, 0);
      }
    }
    __builtin_amdgcn_s_setprio(0);

    // counted wait: allow this iter's 3 staging loads outstanding; everything older
    // (incl. tile t+1, staged last iter) must be complete. Tail: full drain.
    if (kt + 128 < SEGLEN) asm volatile("s_waitcnt vmcnt(3)" ::: "memory");
    else                   asm volatile("s_waitcnt vmcnt(0)" ::: "memory");
    __builtin_amdgcn_s_barrier();
    __builtin_amdgcn_sched_barrier(0);

    buf = (buf == 2) ? 0 : buf + 1;
    sb  = (sb == 2) ? 0 : sb + 1;
  }

  // epilogue: l for q-row quad*4+r sits in lane (quad,0)'s Oacc[5][r] (col 0 = d-row 80)
  f32x4 linv;
  linv.x = 1.0f / __shfl(Oacc[5].x, quad << 4, 64);
  linv.y = 1.0f / __shfl(Oacc[5].y, quad << 4, 64);
  linv.z = 1.0f / __shfl(Oacc[5].z, quad << 4, 64);
  linv.w = 1.0f / __shfl(Oacc[5].w, quad << 4, 64);
  #pragma unroll
  for (int n = 0; n < 5; ++n) {
    int rowb = q0b + w * 16 + quad * 4;
    int col = h * HD + n * 16 + lr;
    attnO[(size_t)(rowb + 0) * EMB + col] = f2h(Oacc[n].x * linv.x);
    attnO[(size_t)(rowb + 1) * EMB + col] = f2h(Oacc[n].y * linv.y);
    attnO[(size_t)(rowb + 2) * EMB + col] = f2h(Oacc[n].z * linv.z);
    attnO[(size_t)(rowb + 3) * EMB + col] = f2h(Oacc[n].w * linv.w);
  }
}

extern "C" void kernel_launch(void* const* d_in, const int* in_sizes, int n_in,
                              void* d_out, int out_size, void* d_ws, size_t ws_size,
                              hipStream_t stream) {
  const float* hs     = (const float*)d_in[0];
  const float* w_qkv  = (const float*)d_in[1];
  const float* b_qkv  = (const float*)d_in[2];
  const float* w_proj = (const float*)d_in[3];
  const float* b_proj = (const float*)d_in[4];
  const float* cosp   = (const float*)d_in[5];
  const float* sinp   = (const float*)d_in[6];
  float* out = (float*)d_out;

  char* p = (char*)d_ws;
  auto take = [&](size_t bytes) { char* q = p; p += (bytes + 255) & ~(size_t)255; return q; };
  u16* hsH    = (u16*)take((size_t)SEQ * EMB * 2);
  u16* wqkvH  = (u16*)take((size_t)O3 * EMB * 2);
  u16* wprojH = (u16*)take((size_t)EMB * EMB * 2);
  u16* qkvO   = (u16*)take((size_t)SEQ * O3 * 2);
  u16* Qp     = (u16*)take((size_t)NH * SEQ * HDP * 2);
  u16* Kp     = (u16*)take((size_t)NH * SEQ * HDP * 2);
  u16* Vt     = (u16*)take((size_t)NH * HD * SEQ * 2);
  u16* attnH  = (u16*)take((size_t)SEQ * EMB * 2);

  int ncvt = (CVT_N1 + CVT_N2 + CVT_N3) / 256;
  cvt_all_kernel<<<ncvt, 256, 0, stream>>>(hs, w_qkv, w_proj, hsH, wqkvH, wprojH);

  // QKV GEMM: 256^2 tile, single-region K-tiles + XCD swizzle. 240 blocks = 1/CU.
  gemm256_kernel<<<dim3(O3 / 256, SEQ / 256), 512, 0, stream>>>(hsH, wqkvH, b_qkv, qkvO, O3, EMB);

  rope_reorg_kernel<<<dim3(SEQ / 64, NH), 256, 0, stream>>>(qkvO, cosp, sinp, Qp, Kp, Vt);

  // attn: 128-q blocks (8 waves), triple-buffered pipeline + XCD swizzle. 512 blocks = 2/CU.
  attn_kernel<<<dim3(SEGLEN / 128, NH, NSEG), 512, 0, stream>>>(Qp, Kp, Vt, attnH);

  // proj GEMM: 128^2 tile + XCD swizzle (320 blocks, 40/XCD)
  gemm_bias_kernel<1><<<dim3(EMB / 128, SEQ / 128), 256, 0, stream>>>(attnH, wprojH, b_proj, out, EMB, EMB);
}

// Round 7
// 225.328 us; speedup vs baseline: 1.0413x; 1.0413x over previous
//
#include <hip/hip_runtime.h>

#define SEQ   4096
#define EMB   1280
#define NH    16
#define HD    80
#define HDP   96
#define O3    3840
#define SEGLEN 1024
#define NSEG  4
// sqrt(80) * log2(e): scores computed in log2 domain -> softmax uses native v_exp_f32 (exp2)
#define QSCALE (8.94427190999915878564f * 1.44269504088896340736f)

typedef unsigned short u16;
typedef __attribute__((ext_vector_type(8))) _Float16 f16x8;
typedef __attribute__((ext_vector_type(4))) _Float16 f16x4;
typedef __attribute__((ext_vector_type(2))) __fp16   h16x2;
typedef __attribute__((ext_vector_type(4))) float    f32x4;

__device__ __forceinline__ float ex2(float x) { return __builtin_amdgcn_exp2f(x); }

__device__ __forceinline__ u16 f2h(float f) {
  union { _Float16 h; u16 u; } v; v.h = (_Float16)f; return v.u;
}
__device__ __forceinline__ float h2f(u16 b) {
  union { u16 u; _Float16 h; } v; v.u = b; return (float)v.h;
}
__device__ __forceinline__ f32x4 exp2_4(f32x4 x) {
  f32x4 r; r.x = ex2(x.x); r.y = ex2(x.y); r.z = ex2(x.z); r.w = ex2(x.w); return r;
}
__device__ __forceinline__ f16x4 pk4(f32x4 s) {
  union { h16x2 h[2]; f16x4 f; } u;
  u.h[0] = __builtin_amdgcn_cvt_pkrtz(s.x, s.y);
  u.h[1] = __builtin_amdgcn_cvt_pkrtz(s.z, s.w);
  return u.f;
}
// async global->LDS, 16B per lane. LDS dest must be wave-uniform base + lane*16.
__device__ __forceinline__ void gl2lds16(const u16* g, u16* l) {
  __builtin_amdgcn_global_load_lds(
      (const __attribute__((address_space(1))) unsigned int*)g,
      (__attribute__((address_space(3))) unsigned int*)l, 16, 0, 0);
}

// ---------------- fused fp32 -> fp16 convert for hs, w_qkv, w_proj ----------------
#define CVT_N1 (SEQ * EMB / 4)
#define CVT_N2 (O3 * EMB / 4)
#define CVT_N3 (EMB * EMB / 4)
__global__ void cvt_all_kernel(const float* __restrict__ a, const float* __restrict__ b,
                               const float* __restrict__ c, u16* __restrict__ oa,
                               u16* __restrict__ ob, u16* __restrict__ oc) {
  int i = blockIdx.x * blockDim.x + threadIdx.x;
  const float* src; u16* dst; int j = i;
  if (j < CVT_N1)                { src = a; dst = oa; }
  else if (j < CVT_N1 + CVT_N2)  { src = b; dst = ob; j -= CVT_N1; }
  else                           { src = c; dst = oc; j -= CVT_N1 + CVT_N2; }
  float4 f = ((const float4*)src)[j];
  union { u16 h[4]; uint2 v; } o;
  o.h[0] = f2h(f.x); o.h[1] = f2h(f.y); o.h[2] = f2h(f.z); o.h[3] = f2h(f.w);
  ((uint2*)dst)[j] = o.v;
}

// ---------------- fp16 MFMA GEMM (128x128 tile, 2-barrier) -- kept for proj ----------------
// XCD-chunked swizzle: grid must be divisible by 8 (proj: 10x32=320 -> 40 blocks/XCD,
// bm in [4x,4x+4) per XCD -> A-panel L2 locality).
template<int OUTF>
__global__ __launch_bounds__(256)
void gemm_bias_kernel(const u16* __restrict__ A, const u16* __restrict__ W,
                      const float* __restrict__ bias, void* __restrict__ Cout,
                      int N, int K) {
  __shared__ u16 As[128][64];
  __shared__ u16 Bs[128][64];
  const int tid  = threadIdx.x;
  const int flat = blockIdx.x + gridDim.x * blockIdx.y;
  const int cpx  = (gridDim.x * gridDim.y) >> 3;
  const int nid  = (flat & 7) * cpx + (flat >> 3);
  const int bm   = nid / gridDim.x, bn = nid % gridDim.x;
  const int lane = tid & 63;
  const int wid  = tid >> 6;
  const int wm   = (wid >> 1) * 64, wn = (wid & 1) * 64;
  const int lr   = lane & 15, quad = lane >> 4;

  f32x4 acc[4][4];
  const f32x4 z4 = {0.f, 0.f, 0.f, 0.f};
  #pragma unroll
  for (int i = 0; i < 4; ++i)
    #pragma unroll
    for (int j = 0; j < 4; ++j) acc[i][j] = z4;

  const int arow = tid >> 3;                       // 0..31
  const int acol = (((tid & 7) ^ (arow & 7)) * 8); // swizzled GLOBAL col chunk
  const u16* Ab = A + (size_t)(bm * 128) * K;
  const u16* Wb = W + (size_t)(bn * 128) * K;
  u16* AsL = &As[0][0] + tid * 8;
  u16* BsL = &Bs[0][0] + tid * 8;

  for (int kt = 0; kt < K; kt += 64) {
    #pragma unroll
    for (int r = 0; r < 4; ++r) {
      gl2lds16(&Ab[(size_t)(arow + r * 32) * K + kt + acol], AsL + r * 2048);
      gl2lds16(&Wb[(size_t)(arow + r * 32) * K + kt + acol], BsL + r * 2048);
    }
    __syncthreads();
    #pragma unroll
    for (int k32 = 0; k32 < 2; ++k32) {
      const int c = (((k32 * 4 + quad) ^ (lr & 7)) * 8);
      f16x8 aF[4], bF[4];
      #pragma unroll
      for (int i = 0; i < 4; ++i) {
        aF[i] = *(const f16x8*)&As[wm + i * 16 + lr][c];
        bF[i] = *(const f16x8*)&Bs[wn + i * 16 + lr][c];
      }
      #pragma unroll
      for (int i = 0; i < 4; ++i)
        #pragma unroll
        for (int j = 0; j < 4; ++j)
          acc[i][j] = __builtin_amdgcn_mfma_f32_16x16x32_f16(aF[i], bF[j], acc[i][j], 0, 0, 0);
    }
    __syncthreads();
  }

  #pragma unroll
  for (int i = 0; i < 4; ++i) {
    int rowb = bm * 128 + wm + i * 16 + quad * 4;
    #pragma unroll
    for (int j = 0; j < 4; ++j) {
      int col = bn * 128 + wn + j * 16 + lr;
      float bv = bias[col];
      #pragma unroll
      for (int r = 0; r < 4; ++r) {
        float v = acc[i][j][r] + bv;
        if (OUTF) ((float*)Cout)[(size_t)(rowb + r) * N + col] = v;
        else      ((u16*)Cout)[(size_t)(rowb + r) * N + col] = f2h(v);
      }
    }
  }
}

// ---------------- fp16 MFMA GEMM 256x256, BK=64, 8 waves, 2-phase counted-vmcnt schedule ----
// XCD-chunked swizzle: 240 blocks = 8 x 30 -> XCD x gets bm in {2x,2x+1}.
// Per tile t (buf=t&1, nb=buf^1), TWO phases (was 4 in R5, 1 in failed R6):
//  Phase A (mq=0): ds_read bF[2][4] (BOTH k32 sets, reused in phase B: -8 reads/wave/tile)
//                  + aF0[2][4]  (16 x ds_read_b128)
//                  stage B0,B1,A1(t+1) -> nb  (6 gl2lds)
//                  32 MFMA (compiler emits fine-grained lgkmcnt partial waits)
//                  s_barrier  -- all waves' As[buf][0:128) reads retired (consumed by MFMAs)
//  Phase B (mq=1): ds_read aF1[2][4] (8); stage A0(t+2) -> As[buf][0:128) (2 gl2lds)
//                  32 MFMA; s_waitcnt vmcnt(2) (tail: 0); s_barrier
// Ledger: tile t+1's halves staged at (t-1).B [A0] and t.A [B0,B1,A1]; only loads younger
// at t.B's wait are t.B's own 2 -> vmcnt(2) forces t+1 fully resident. Barriers 8->2,
// full lgkm drains 4->0, ds_reads 32->24 per wave per tile.
__global__ __launch_bounds__(512, 2)
void gemm256_kernel(const u16* __restrict__ A, const u16* __restrict__ W,
                    const float* __restrict__ bias, u16* __restrict__ Cout,
                    int N, int K) {
  __shared__ u16 As[2][256][64];   // 64 KiB
  __shared__ u16 Bs[2][256][64];   // 64 KiB
  const int tid  = threadIdx.x;
  const int flat = blockIdx.x + gridDim.x * blockIdx.y;   // bn-fastest dispatch order
  const int cpx  = (gridDim.x * gridDim.y) >> 3;          // blocks per XCD (30)
  const int nid  = (flat & 7) * cpx + (flat >> 3);
  const int bm   = nid / gridDim.x, bn = nid % gridDim.x;
  const int lane = tid & 63;
  const int wid  = tid >> 6;       // 0..7
  const int wm   = wid >> 2;       // 0..1 (M half within wave grid)
  const int wn   = wid & 3;        // 0..3
  const int lr   = lane & 15, quad = lane >> 4;
  const int NT   = K >> 6;         // K-tiles of 64

  const u16* Ab = A + (size_t)(bm * 256) * K;
  const u16* Wb = W + (size_t)(bn * 256) * K;

  // staging lane geometry: one gl2lds round = 64 rows x 64 cols (512 lanes x 16B)
  const int srr  = tid >> 3;                        // 0..63
  const int scol = ((tid & 7) ^ (srr & 7)) << 3;    // pre-swizzled global col chunk
  const u16* ApL = Ab + (size_t)srr * K + scol;
  const u16* WpL = Wb + (size_t)srr * K + scol;

  auto stA = [&](int b, int row0, int t) {
    gl2lds16(ApL + (size_t)row0 * K + t * 64,        &As[b][row0][0]      + tid * 8);
    gl2lds16(ApL + (size_t)(row0 + 64) * K + t * 64, &As[b][row0 + 64][0] + tid * 8);
  };
  auto stB = [&](int b, int row0, int t) {
    gl2lds16(WpL + (size_t)row0 * K + t * 64,        &Bs[b][row0][0]      + tid * 8);
    gl2lds16(WpL + (size_t)(row0 + 64) * K + t * 64, &Bs[b][row0 + 64][0] + tid * 8);
  };

  f32x4 acc[8][4];
  const f32x4 z4 = {0.f, 0.f, 0.f, 0.f};
  #pragma unroll
  for (int i = 0; i < 8; ++i)
    #pragma unroll
    for (int j = 0; j < 4; ++j) acc[i][j] = z4;

  // fragment column offsets for k32 = 0,1 (swizzled chunk layout)
  const int c0 = (((0 * 4 + quad) ^ (lr & 7)) << 3);
  const int c1 = (((1 * 4 + quad) ^ (lr & 7)) << 3);

  // prologue: tile0 full (8 loads) + tile1 A0 (2 loads); wait tile0, keep tile1-A0 in flight
  stA(0, 0, 0); stA(0, 128, 0);
  stB(0, 0, 0); stB(0, 128, 0);
  stA(1, 0, 1);
  asm volatile("s_waitcnt vmcnt(2)" ::: "memory");
  __builtin_amdgcn_s_barrier();
  __builtin_amdgcn_sched_barrier(0);

  for (int t = 0; t < NT; ++t) {
    const int buf = t & 1, nb = buf ^ 1;

    // ---------- phase A (mq = 0) ----------
    // ds-load both-k32 B fragments (kept live through phase B) + mq=0 A fragments
    f16x8 bF[2][4], aF0[2][4];
    #pragma unroll
    for (int j = 0; j < 4; ++j) {
      bF[0][j] = *(const f16x8*)&Bs[buf][wn * 64 + j * 16 + lr][c0];
      bF[1][j] = *(const f16x8*)&Bs[buf][wn * 64 + j * 16 + lr][c1];
    }
    #pragma unroll
    for (int i = 0; i < 4; ++i) {
      aF0[0][i] = *(const f16x8*)&As[buf][wm * 64 + i * 16 + lr][c0];
      aF0[1][i] = *(const f16x8*)&As[buf][wm * 64 + i * 16 + lr][c1];
    }
    __builtin_amdgcn_sched_barrier(0);
    // stage three half-tiles of t+1 into nb (regions last read at tile t-1)
    if (t + 1 < NT) { stB(nb, 0, t + 1); stB(nb, 128, t + 1); stA(nb, 128, t + 1); }
    __builtin_amdgcn_sched_barrier(0);
    __builtin_amdgcn_s_setprio(1);
    #pragma unroll
    for (int k32 = 0; k32 < 2; ++k32)
      #pragma unroll
      for (int i = 0; i < 4; ++i)
        #pragma unroll
        for (int j = 0; j < 4; ++j)
          acc[i][j] = __builtin_amdgcn_mfma_f32_16x16x32_f16(aF0[k32][i], bF[k32][j], acc[i][j], 0, 0, 0);
    __builtin_amdgcn_s_setprio(0);
    __builtin_amdgcn_sched_barrier(0);
    // barrier1: all waves' As[buf][0:128) reads retired -> safe to overwrite in phase B
    __builtin_amdgcn_s_barrier();

    // ---------- phase B (mq = 1) ----------
    f16x8 aF1[2][4];
    #pragma unroll
    for (int i = 0; i < 4; ++i) {
      aF1[0][i] = *(const f16x8*)&As[buf][128 + wm * 64 + i * 16 + lr][c0];
      aF1[1][i] = *(const f16x8*)&As[buf][128 + wm * 64 + i * 16 + lr][c1];
    }
    __builtin_amdgcn_sched_barrier(0);
    if (t + 2 < NT) stA(buf, 0, t + 2);
    __builtin_amdgcn_sched_barrier(0);
    __builtin_amdgcn_s_setprio(1);
    #pragma unroll
    for (int k32 = 0; k32 < 2; ++k32)
      #pragma unroll
      for (int i = 0; i < 4; ++i)
        #pragma unroll
        for (int j = 0; j < 4; ++j)
          acc[4 + i][j] = __builtin_amdgcn_mfma_f32_16x16x32_f16(aF1[k32][i], bF[k32][j], acc[4 + i][j], 0, 0, 0);
    __builtin_amdgcn_s_setprio(0);
    // counted vmcnt: only t's phase-B A0(t+2) loads (2) may remain in flight
    if (t < NT - 2) asm volatile("s_waitcnt vmcnt(2)" ::: "memory");
    else            asm volatile("s_waitcnt vmcnt(0)" ::: "memory");
    __builtin_amdgcn_s_barrier();
    __builtin_amdgcn_sched_barrier(0);
  }

  // epilogue: bias add, fp16 store
  #pragma unroll
  for (int mq = 0; mq < 2; ++mq) {
    #pragma unroll
    for (int i = 0; i < 4; ++i) {
      const int rowb = bm * 256 + mq * 128 + wm * 64 + i * 16 + quad * 4;
      #pragma unroll
      for (int j = 0; j < 4; ++j) {
        const int col = bn * 256 + wn * 64 + j * 16 + lr;
        const float bv = bias[col];
        #pragma unroll
        for (int r = 0; r < 4; ++r)
          Cout[(size_t)(rowb + r) * N + col] = f2h(acc[mq * 4 + i][j][r] + bv);
      }
    }
  }
}

// ---------------- RoPE + layout reorg (fully vectorized IO via LDS) ----------------
// block = (64 s-rows, 1 head). qkv[s][3840] -> Qp[h][s][96] (*QSCALE), Kp[h][s][96], Vt[h][d][s]
__global__ __launch_bounds__(256)
void rope_reorg_kernel(const u16* __restrict__ qkv, const float* __restrict__ cosp,
                       const float* __restrict__ sinp, u16* __restrict__ Qp,
                       u16* __restrict__ Kp, u16* __restrict__ Vt) {
  __shared__ u16 Qs[64][80];
  __shared__ u16 Ks[64][80];
  __shared__ u16 Vs[64][88];   // stride 88: rows 16B aligned; col reads conflict-light
  const int tid = threadIdx.x;
  const int s0 = blockIdx.x * 64;
  const int h  = blockIdx.y;

  // load: 64 rows x 80 u16 x 3 arrays, uint4 vectorized
  for (int t = tid; t < 640; t += 256) {
    int r = t / 10, c = (t % 10) * 8;
    size_t g = (size_t)(s0 + r) * O3 + h * HD + c;
    *(uint4*)&Qs[r][c] = *(const uint4*)&qkv[g];
    *(uint4*)&Ks[r][c] = *(const uint4*)&qkv[g + EMB];
    *(uint4*)&Vs[r][c] = *(const uint4*)&qkv[g + 2 * EMB];
  }
  __syncthreads();

  // phase A: rope, 4 outputs per slot, uint2 writes
  for (int t = tid; t < 64 * 24; t += 256) {
    int r = t / 24, d4 = (t % 24) * 4;
    int s = s0 + r;
    size_t po = ((size_t)h * SEQ + s) * HDP + d4;
    if (d4 >= HD) {
      uint2 z = make_uint2(0, 0);
      *(uint2*)&Qp[po] = z; *(uint2*)&Kp[po] = z;
      continue;
    }
    float4 cv = *(const float4*)&cosp[(size_t)s * HD + d4];
    float4 sv = *(const float4*)&sinp[(size_t)s * HD + d4];
    int dp4 = (d4 < 40) ? d4 + 40 : d4 - 40;
    float sgn = (d4 < 40) ? -1.f : 1.f;
    union { u16 h[4]; uint2 v; } oq, ok;
    const float* cp = (const float*)&cv;
    const float* sp = (const float*)&sv;
    #pragma unroll
    for (int j = 0; j < 4; ++j) {
      float q  = h2f(Qs[r][d4 + j]),  k  = h2f(Ks[r][d4 + j]);
      float qp = h2f(Qs[r][dp4 + j]), kp = h2f(Ks[r][dp4 + j]);
      oq.h[j] = f2h((q * cp[j] + sgn * qp * sp[j]) * QSCALE);
      ok.h[j] = f2h(k * cp[j] + sgn * kp * sp[j]);
    }
    *(uint2*)&Qp[po] = oq.v;
    *(uint2*)&Kp[po] = ok.v;
  }

  // phase B: V transpose, uint4 writes along s
  for (int t = tid; t < HD * 8; t += 256) {
    int d = t / 8, sc = (t % 8) * 8;
    union { u16 h[8]; uint4 v; } o;
    #pragma unroll
    for (int j = 0; j < 8; ++j) o.h[j] = Vs[sc + j][d];
    *(uint4*)&Vt[((size_t)(h * HD + d)) * SEQ + s0 + sc] = o.v;
  }
}

// ---------------- flash attention: 128q blocks, triple-buffered counted-vmcnt pipeline ----
// block = 128 q x (head, seg), 8 waves x 16 q, 512 threads. S^T = K Q^T; P direct-to-MFMA.
// XCD-chunked swizzle: 512 blocks = 8 x 64 -> each XCD owns 8 complete (h,seg) groups;
// per-XCD K/V working set = 8 x 356KB = 2.9MB < 4MB L2 (was: all groups on all XCDs).
// K_l [3][64][96] per-row chunk swizzle (bank-spread). V_l [3][96][64] 16B-chunk XOR
// swizzle; rows 80..95 ones/zero so row-sum l is a 6th PV acc.
// Pipeline: stage tile t+2 at iter t into buf[(t+2)%3]; end-of-iter s_waitcnt vmcnt(3).
__global__ __launch_bounds__(512)
void attn_kernel(const u16* __restrict__ Qp, const u16* __restrict__ Kp,
                 const u16* __restrict__ Vt, u16* __restrict__ attnO) {
  __shared__ u16 K_l[3][64][96];   // 3 x 12 KiB
  __shared__ u16 V_l[3][96][64];   // 3 x 12 KiB
  const int BUFSZ = 6144;          // u16 per buffer (same for K and V)

  const int tid = threadIdx.x;     // 0..511
  const int lane = tid & 63, w = tid >> 6;   // w 0..7
  const int lr = lane & 15, quad = lane >> 4;
  // XCD-chunked remap: flat = bx + 8*by + 128*bz (dispatch order); nid groups 8 blocks
  // of one (h,seg) pair onto one XCD.
  const int flat = blockIdx.x + 8 * blockIdx.y + 128 * blockIdx.z;
  const int nid  = (flat & 7) * 64 + (flat >> 3);
  const int qb   = nid & 7;
  const int h    = (nid >> 3) & 15;
  const int sg   = nid >> 7;
  const int seg0 = sg * SEGLEN;
  const int q0b = seg0 + qb * 128;

  // Q B-fragments (q already scaled by sqrt(80)*log2e at rope time)
  f16x8 qF[3];
  {
    int qrow = q0b + w * 16 + lr;
    #pragma unroll
    for (int kc = 0; kc < 3; ++kc)
      qF[kc] = *(const f16x8*)&Qp[((size_t)h * SEQ + qrow) * HDP + kc * 32 + quad * 8];
  }
  // force-retire qF loads NOW so the compiler's waitcnt insertion marks them complete
  // before the pipelined loop (else it may inject vmcnt(0) at first use inside the loop)
  asm volatile("" :: "v"(qF[0]), "v"(qF[1]), "v"(qF[2]));
  asm volatile("s_waitcnt vmcnt(0)" ::: "memory");

  // ones/zero pad rows 80..95 of each V buffer (row 80 = 1.0h). 2 u16/thread/buffer.
  {
    u16 val = (tid < 32) ? (u16)0x3C00 : (u16)0;
    #pragma unroll
    for (int b = 0; b < 3; ++b) {
      u16* q = &V_l[0][0][0] + b * BUFSZ + 80 * 64 + tid * 2;
      q[0] = val; q[1] = val;
    }
  }

  // staging slot map: 3 rounds x 512 threads = 1536 slots/tile.
  //   s <  768 : K slot s   (r=s/12, c=s%12, chunk-swizzled source)
  //   s < 1408 : V slot s-768 (rv=sv/8, cv=sv%8, XOR-swizzled source)
  //   s >=1408 : duplicate of V slot s-1408 (uniform count filler; same data, same dest)
  const u16* Kbase = Kp + ((size_t)h * SEQ + seg0) * HDP;
  const u16* Vbase = Vt + (size_t)h * HD * SEQ + seg0;
  const u16* pG[3]; u16* dB[3]; int gAdv[3];
  #pragma unroll
  for (int t = 0; t < 3; ++t) {
    int s = t * 512 + tid;
    if (s < 768) {
      int r = s / 12, c = s % 12;
      int ck = (c & ~3) | ((c & 3) ^ ((r >> 1) & 3));  // K chunk swizzle (bank-spread)
      pG[t] = Kbase + (size_t)r * HDP + ck * 8;
      dB[t] = &K_l[0][0][0] + s * 8;
      gAdv[t] = 64 * HDP;
    } else {
      int sv = (s < 1408) ? s - 768 : s - 1408;
      int rv = sv / 8, cv = sv % 8;
      int cg = cv ^ (rv & 7);                          // V XOR chunk swizzle
      pG[t] = Vbase + (size_t)rv * SEQ + cg * 8;
      dB[t] = &V_l[0][0][0] + sv * 8;
      gAdv[t] = 64;
    }
  }

  // stage one K/V tile into buffer b (3 gl2lds/thread), advance global ptrs by 64 keys
  auto stage_adv = [&](int b) {
    #pragma unroll
    for (int t = 0; t < 3; ++t) {
      gl2lds16(pG[t], dB[t] + b * BUFSZ);
      pG[t] += gAdv[t];
    }
  };

  const f32x4 z4 = {0.f, 0.f, 0.f, 0.f};
  float m_r = -3.0e38f;
  f32x4 Oacc[6];   // [0..4] = output cols, [5] = MFMA row-sum (ones column of V)
  #pragma unroll
  for (int n = 0; n < 6; ++n) Oacc[n] = z4;

  const int kswz = (lr >> 1) & 3;  // == ((ct*16+lr)>>1)&3 for all ct

  // prologue: stage tiles 0,1; wait tile0 (3 newest = tile1 may fly); drain ds_writes
  stage_adv(0);
  stage_adv(1);
  asm volatile("s_waitcnt vmcnt(3) lgkmcnt(0)" ::: "memory");
  __builtin_amdgcn_s_barrier();
  __builtin_amdgcn_sched_barrier(0);

  int buf = 0, sb = 2;
  for (int kt = 0; kt < SEGLEN; kt += 64) {
    // issue stage of tile t+2 into buf[(t+2)%3]; its dest buffer's readers finished
    // at iter t-1 (barrier-separated). Completes by end of iter t+1 (vmcnt(3) chain).
    if (kt + 128 < SEGLEN) stage_adv(sb);

    const u16* kb = &K_l[0][0][0] + buf * BUFSZ;
    const u16* vb = &V_l[0][0][0] + buf * BUFSZ;

    // S^T = K Q^T: lane holds scores for q=lr at c = ct*16 + quad*4 + r (log2 domain)
    f32x4 S[4];
    __builtin_amdgcn_s_setprio(1);
    #pragma unroll
    for (int ct = 0; ct < 4; ++ct) {
      S[ct] = z4;
      #pragma unroll
      for (int kc = 0; kc < 3; ++kc) {
        f16x8 kF = *(const f16x8*)&kb[(ct * 16 + lr) * 96 + kc * 32 + ((quad ^ kswz) << 3)];
        S[ct] = __builtin_amdgcn_mfma_f32_16x16x32_f16(kF, qF[kc], S[ct], 0, 0, 0);
      }
    }
    __builtin_amdgcn_s_setprio(0);

    // online softmax (exp2 domain): max tree + 2 shuffles; row-sum comes from PV MFMA
    float mx = fmaxf(fmaxf(S[0].x, S[0].y), fmaxf(S[0].z, S[0].w));
    #pragma unroll
    for (int ct = 1; ct < 4; ++ct)
      mx = fmaxf(mx, fmaxf(fmaxf(S[ct].x, S[ct].y), fmaxf(S[ct].z, S[ct].w)));
    mx = fmaxf(mx, __shfl_xor(mx, 16, 64));
    mx = fmaxf(mx, __shfl_xor(mx, 32, 64));
    float mnew = fmaxf(m_r, mx);
    float alpha = ex2(m_r - mnew);
    m_r = mnew;

    f32x4 mv = {mnew, mnew, mnew, mnew};
    #pragma unroll
    for (int ct = 0; ct < 4; ++ct) S[ct] = exp2_4(S[ct] - mv);

    // rescale history only when some lane's max moved (wave-uniform skip)
    if (__ballot(alpha != 1.0f)) {
      f32x4 al;
      al.x = __shfl(alpha, quad * 4 + 0, 64);
      al.y = __shfl(alpha, quad * 4 + 1, 64);
      al.z = __shfl(alpha, quad * 4 + 2, 64);
      al.w = __shfl(alpha, quad * 4 + 3, 64);
      #pragma unroll
      for (int n = 0; n < 6; ++n) Oacc[n] *= al;
    }

    // P fragments via packed cvt, direct A-operand of 16x16x16 (k=quad*4+j == c=quad*4+r)
    f16x4 pF[4];
    #pragma unroll
    for (int ct = 0; ct < 4; ++ct) pF[ct] = pk4(S[ct]);

    // PV: vF from swizzled V_l; n=5 hits the ones/zero rows -> row-sum accumulator
    __builtin_amdgcn_s_setprio(1);
    #pragma unroll
    for (int ct = 0; ct < 4; ++ct) {
      const int cchunk = 2 * ct + (quad >> 1);
      #pragma unroll
      for (int n = 0; n < 6; ++n) {
        int vrow = n * 16 + lr;
        const u16* vp = vb + vrow * 64 + ((cchunk ^ (vrow & 7)) << 3) + ((quad & 1) << 2);
        f16x4 vF = *(const f16x4*)vp;
        Oacc[n] = __builtin_amdgcn_mfma_f32_16x16x16f16(pF[ct], vF, Oacc[n], 0, 0, 0);
      }
    }
    __builtin_amdgcn_s_setprio(0);

    // counted wait: allow this iter's 3 staging loads outstanding; everything older
    // (incl. tile t+1, staged last iter) must be complete. Tail: full drain.
    if (kt + 128 < SEGLEN) asm volatile("s_waitcnt vmcnt(3)" ::: "memory");
    else                   asm volatile("s_waitcnt vmcnt(0)" ::: "memory");
    __builtin_amdgcn_s_barrier();
    __builtin_amdgcn_sched_barrier(0);

    buf = (buf == 2) ? 0 : buf + 1;
    sb  = (sb == 2) ? 0 : sb + 1;
  }

  // epilogue: l for q-row quad*4+r sits in lane (quad,0)'s Oacc[5][r] (col 0 = d-row 80)
  f32x4 linv;
  linv.x = 1.0f / __shfl(Oacc[5].x, quad << 4, 64);
  linv.y = 1.0f / __shfl(Oacc[5].y, quad << 4, 64);
  linv.z = 1.0f / __shfl(Oacc[5].z, quad << 4, 64);
  linv.w = 1.0f / __shfl(Oacc[5].w, quad << 4, 64);
  #pragma unroll
  for (int n = 0; n < 5; ++n) {
    int rowb = q0b + w * 16 + quad * 4;
    int col = h * HD + n * 16 + lr;
    attnO[(size_t)(rowb + 0) * EMB + col] = f2h(Oacc[n].x * linv.x);
    attnO[(size_t)(rowb + 1) * EMB + col] = f2h(Oacc[n].y * linv.y);
    attnO[(size_t)(rowb + 2) * EMB + col] = f2h(Oacc[n].z * linv.z);
    attnO[(size_t)(rowb + 3) * EMB + col] = f2h(Oacc[n].w * linv.w);
  }
}

extern "C" void kernel_launch(void* const* d_in, const int* in_sizes, int n_in,
                              void* d_out, int out_size, void* d_ws, size_t ws_size,
                              hipStream_t stream) {
  const float* hs     = (const float*)d_in[0];
  const float* w_qkv  = (const float*)d_in[1];
  const float* b_qkv  = (const float*)d_in[2];
  const float* w_proj = (const float*)d_in[3];
  const float* b_proj = (const float*)d_in[4];
  const float* cosp   = (const float*)d_in[5];
  const float* sinp   = (const float*)d_in[6];
  float* out = (float*)d_out;

  char* p = (char*)d_ws;
  auto take = [&](size_t bytes) { char* q = p; p += (bytes + 255) & ~(size_t)255; return q; };
  u16* hsH    = (u16*)take((size_t)SEQ * EMB * 2);
  u16* wqkvH  = (u16*)take((size_t)O3 * EMB * 2);
  u16* wprojH = (u16*)take((size_t)EMB * EMB * 2);
  u16* qkvO   = (u16*)take((size_t)SEQ * O3 * 2);
  u16* Qp     = (u16*)take((size_t)NH * SEQ * HDP * 2);
  u16* Kp     = (u16*)take((size_t)NH * SEQ * HDP * 2);
  u16* Vt     = (u16*)take((size_t)NH * HD * SEQ * 2);
  u16* attnH  = (u16*)take((size_t)SEQ * EMB * 2);

  int ncvt = (CVT_N1 + CVT_N2 + CVT_N3) / 256;
  cvt_all_kernel<<<ncvt, 256, 0, stream>>>(hs, w_qkv, w_proj, hsH, wqkvH, wprojH);

  // QKV GEMM: 256^2 tile, 2-phase counted-vmcnt schedule + XCD swizzle. 240 blocks = 1/CU.
  gemm256_kernel<<<dim3(O3 / 256, SEQ / 256), 512, 0, stream>>>(hsH, wqkvH, b_qkv, qkvO, O3, EMB);

  rope_reorg_kernel<<<dim3(SEQ / 64, NH), 256, 0, stream>>>(qkvO, cosp, sinp, Qp, Kp, Vt);

  // attn: 128-q blocks (8 waves), triple-buffered pipeline + XCD swizzle. 512 blocks = 2/CU.
  attn_kernel<<<dim3(SEGLEN / 128, NH, NSEG), 512, 0, stream>>>(Qp, Kp, Vt, attnH);

  // proj GEMM: 128^2 tile + XCD swizzle (320 blocks, 40/XCD)
  gemm_bias_kernel<1><<<dim3(EMB / 128, SEQ / 128), 256, 0, stream>>>(attnH, wprojH, b_proj, out, EMB, EMB);
}